// Round 1
// baseline (1274.028 us; speedup 1.0000x reference)
//
#include <hip/hip_runtime.h>

#define BB   2
#define CCH  256
#define HF   96
#define WF   320
#define NYC  7
#define DWT  16384          // 128*128
#define PLANE (HF*WF)       // 30720
#define KDIM (CCH*NYC)      // 1792
#define PPB  8              // positions per block in fused kernel

// ---------------- K1: row cumsum (axis -1) ----------------
__global__ void k_rowcum(const float* __restrict__ f, float* __restrict__ ii) {
    int row = blockIdx.x * blockDim.x + threadIdx.x;   // (b*C + c)*H + y
    if (row >= BB * CCH * HF) return;
    const float* src = f  + (size_t)row * WF;
    float*       dst = ii + (size_t)row * WF;
    float carry = 0.f;
    for (int i = 0; i < WF; i += 4) {
        float4 v = *reinterpret_cast<const float4*>(src + i);
        float a0 = carry + v.x;
        float a1 = a0 + v.y;
        float a2 = a1 + v.z;
        float a3 = a2 + v.w;
        float4 o = make_float4(a0, a1, a2, a3);
        *reinterpret_cast<float4*>(dst + i) = o;
        carry = a3;
    }
}

// ---------------- K2: col cumsum (axis -2), in place ----------------
__global__ void k_colcum(float* __restrict__ ii) {
    int t = blockIdx.x * blockDim.x + threadIdx.x;     // (b*C + c)*W + x
    if (t >= BB * CCH * WF) return;
    int x  = t % WF;
    int bc = t / WF;
    float* p = ii + (size_t)bc * PLANE + x;
    float acc = 0.f;
    for (int y = 0; y < HF; ++y) {
        acc += p[(size_t)y * WF];
        p[(size_t)y * WF] = acc;
    }
}

// ---------------- K3: transpose ii (B,C,H,W) -> ii_t (B,H,W,C) ----------------
__global__ void k_transpose(const float* __restrict__ ii, float* __restrict__ iit) {
    __shared__ float tile[32][33];
    int x0 = blockIdx.x * 32;          // W tile
    int c0 = blockIdx.y * 32;          // C tile
    int by = blockIdx.z;               // b*HF + y
    int b  = by / HF;
    int y  = by % HF;
    const float* src = ii  + (size_t)b * CCH * PLANE + (size_t)y * WF;
    float*       dst = iit + (size_t)by * WF * CCH;
    int tx = threadIdx.x;              // 0..31
    int ty = threadIdx.y;              // 0..7
    #pragma unroll
    for (int i = 0; i < 4; ++i) {
        int c = c0 + ty + 8 * i;
        tile[ty + 8 * i][tx] = src[(size_t)c * PLANE + x0 + tx];
    }
    __syncthreads();
    #pragma unroll
    for (int i = 0; i < 4; ++i) {
        int x = x0 + ty + 8 * i;
        dst[(size_t)x * CCH + c0 + tx] = tile[tx][ty + 8 * i];
    }
}

// ---------------- K4: geometry -> g_tl, g_br, g_tr, g_bl ----------------
__global__ void k_geom(const float* __restrict__ calib, const float* __restrict__ grid,
                       float* __restrict__ gtl, float* __restrict__ gbr,
                       float* __restrict__ gtr, float* __restrict__ gbl) {
    int t = blockIdx.x * blockDim.x + threadIdx.x;
    if (t >= BB * NYC * DWT) return;
    int dw = t % DWT;
    int by = t / DWT;
    int y  = by % NYC;
    int b  = by / NYC;
    int d  = dw >> 7;
    int w  = dw & 127;
    const float* cb = calib + b * 12;

    float c0=cb[0],c1=cb[1],c2=cb[2],c3=cb[3];
    float c4=cb[4],c5=cb[5],c6=cb[6],c7=cb[7];
    float c8=cb[8],c9=cb[9],c10=cb[10],c11=cb[11];

    auto ncp = [&](int yy, int i, int j, float& ox, float& oy) {
        const float* g = grid + (((size_t)b * 129 + i) * 129 + j) * 3;
        float gx = g[0];
        float gy = g[1] + (0.5f * (float)yy - 2.0f);
        float gz = g[2];
        float h0 = c0*gx + c1*gy + c2*gz + c3;
        float h1 = c4*gx + c5*gy + c6*gz + c7;
        float h2 = c8*gx + c9*gy + c10*gz + c11;
        float ix = h0 / h2;
        float iy = h1 / h2;
        float nx = 2.0f * ix / ((float)WF / 0.125f) - 1.0f;   // /2560
        float ny = 2.0f * iy / ((float)HF / 0.125f) - 1.0f;   // /768
        ox = fminf(fmaxf(nx, -1.f), 1.f);
        oy = fminf(fmaxf(ny, -1.f), 1.f);
    };

    float ax, ay, bx, byy, mx1, my1, mx2, my2;
    ncp(y,     d,     w,     ax,  ay);
    ncp(y,     d + 1, w,     bx,  byy);
    float minx = fminf(ax, bx), miny = fminf(ay, byy);
    ncp(y + 1, d + 1, w + 1, mx1, my1);
    ncp(y + 1, d,     w + 1, mx2, my2);
    float maxx = fmaxf(mx1, mx2), maxy = fmaxf(my1, my2);

    size_t o = (size_t)t * 2;
    gtl[o] = minx; gtl[o + 1] = miny;
    gbr[o] = maxx; gbr[o + 1] = maxy;
    gtr[o] = maxx; gtr[o + 1] = miny;
    gbl[o] = minx; gbl[o + 1] = maxy;
}

// ---------------- K5: fused bilinear 4-corner sample + matvec + bias + relu ----
// FAST: sample from ii_t (B,H,W,C) coalesced over c; else from ii (B,C,H,W)
template<bool FAST>
__global__ __launch_bounds__(256)
void k_sample_mm(const float* __restrict__ iisrc,
                 const float* __restrict__ gtl, const float* __restrict__ gbr,
                 const float* __restrict__ w, const float* __restrict__ bias,
                 float* __restrict__ ortho) {
    __shared__ float vox[PPB][KDIM];           // 57344 B
    __shared__ int   tidx[PPB][NYC][16];       // 3584 B
    __shared__ float twgt[PPB][NYC][16];       // 3584 B

    int t   = threadIdx.x;
    int pg0 = blockIdx.x * PPB;
    int b   = pg0 / DWT;
    int dw0 = pg0 % DWT;

    // build tap tables: 56 (p,y) entries
    if (t < PPB * NYC) {
        int p = t / NYC, y = t % NYC;
        size_t gi = (((size_t)(b * NYC + y)) * DWT + dw0 + p) * 2;
        float g0 = gtl[gi], g1 = gtl[gi + 1];
        float g2 = gbr[gi], g3 = gbr[gi + 1];
        float area = (g2 - g0) * (g3 - g1) * ((float)HF * (float)WF * 0.25f) + 1e-6f;
        float inv  = (area > 1e-6f) ? (1.0f / area) : 0.0f;
        const float sgn[4] = {1.f, 1.f, -1.f, -1.f};
        float px[4] = {g0, g2, g2, g0};
        float py[4] = {g1, g3, g1, g3};
        #pragma unroll
        for (int q = 0; q < 4; ++q) {
            float x  = (px[q] + 1.0f) * ((float)WF * 0.5f) - 0.5f;
            float yy = (py[q] + 1.0f) * ((float)HF * 0.5f) - 0.5f;
            float x0f = floorf(x), y0f = floorf(yy);
            float wx = x - x0f, wy = yy - y0f;
            float wq[4] = {(1.f-wx)*(1.f-wy), wx*(1.f-wy), (1.f-wx)*wy, wx*wy};
            #pragma unroll
            for (int s = 0; s < 4; ++s) {
                float xi = x0f + (float)(s & 1);
                float yi = y0f + (float)(s >> 1);
                bool valid = (xi >= 0.f) && (xi < (float)WF) && (yi >= 0.f) && (yi < (float)HF);
                int xc = (int)fminf(fmaxf(xi, 0.f), (float)(WF - 1));
                int yc = (int)fminf(fmaxf(yi, 0.f), (float)(HF - 1));
                tidx[p][y][q * 4 + s] = yc * WF + xc;
                twgt[p][y][q * 4 + s] = valid ? (wq[s] * sgn[q] * inv) : 0.0f;
            }
        }
    }
    __syncthreads();

    // phase 1: vox[p][c*7+y], thread = channel c
    {
        int c = t;
        const float* base = FAST ? (iisrc + (size_t)b * PLANE * CCH)
                                 : (iisrc + ((size_t)(b * CCH + c)) * PLANE);
        for (int p = 0; p < PPB; ++p) {
            #pragma unroll
            for (int y = 0; y < NYC; ++y) {
                float acc = 0.f;
                #pragma unroll
                for (int s = 0; s < 16; ++s) {
                    int   idx = tidx[p][y][s];
                    float wg  = twgt[p][y][s];
                    float v   = FAST ? base[(size_t)idx * CCH + c] : base[idx];
                    acc += wg * v;
                }
                vox[p][c * NYC + y] = acc;
            }
        }
    }
    __syncthreads();

    // phase 2: thread = output channel co, matvec over K=1792
    int co = t;
    float acc[PPB];
    float bv = bias[co];
    #pragma unroll
    for (int p = 0; p < PPB; ++p) acc[p] = bv;

    const float4* wrow = reinterpret_cast<const float4*>(w + (size_t)co * KDIM);
    for (int k4 = 0; k4 < KDIM / 4; ++k4) {
        float4 wv = wrow[k4];
        #pragma unroll
        for (int p = 0; p < PPB; ++p) {
            float4 vv = *reinterpret_cast<const float4*>(&vox[p][k4 * 4]);
            acc[p] += vv.x * wv.x + vv.y * wv.y + vv.z * wv.z + vv.w * wv.w;
        }
    }

    float* orow = ortho + ((size_t)(b * CCH + co)) * DWT + dw0;
    float4 o0 = make_float4(fmaxf(acc[0], 0.f), fmaxf(acc[1], 0.f),
                            fmaxf(acc[2], 0.f), fmaxf(acc[3], 0.f));
    float4 o1 = make_float4(fmaxf(acc[4], 0.f), fmaxf(acc[5], 0.f),
                            fmaxf(acc[6], 0.f), fmaxf(acc[7], 0.f));
    *reinterpret_cast<float4*>(orow)     = o0;
    *reinterpret_cast<float4*>(orow + 4) = o1;
}

extern "C" void kernel_launch(void* const* d_in, const int* in_sizes, int n_in,
                              void* d_out, int out_size, void* d_ws, size_t ws_size,
                              hipStream_t stream) {
    const float* features = (const float*)d_in[0];
    const float* calib    = (const float*)d_in[1];
    const float* grid     = (const float*)d_in[2];
    const float* w        = (const float*)d_in[3];
    const float* bias     = (const float*)d_in[4];

    float* out   = (float*)d_out;
    float* ortho = out;                                   // 2*256*128*128 = 8388608
    float* ii    = out + (size_t)8388608;                 // 2*256*96*320 = 15728640
    float* gtl   = out + (size_t)24117248;                // 2*7*16384*2 = 458752
    float* gbr   = out + (size_t)24576000;
    float* gtr   = out + (size_t)25034752;
    float* gbl   = out + (size_t)25493504;

    float* iit = (float*)d_ws;
    size_t need = (size_t)BB * PLANE * CCH * sizeof(float);   // 62.9 MB
    bool fast = (ws_size >= need);

    k_rowcum<<<(BB * CCH * HF + 255) / 256, 256, 0, stream>>>(features, ii);
    k_colcum<<<(BB * CCH * WF + 255) / 256, 256, 0, stream>>>(ii);
    k_geom  <<<(BB * NYC * DWT + 255) / 256, 256, 0, stream>>>(calib, grid, gtl, gbr, gtr, gbl);

    if (fast) {
        dim3 gT(WF / 32, CCH / 32, BB * HF);   // (10, 8, 192)
        k_transpose<<<gT, dim3(32, 8), 0, stream>>>(ii, iit);
        k_sample_mm<true><<<BB * DWT / PPB, 256, 0, stream>>>(iit, gtl, gbr, w, bias, ortho);
    } else {
        k_sample_mm<false><<<BB * DWT / PPB, 256, 0, stream>>>(ii, gtl, gbr, w, bias, ortho);
    }
}

// Round 2
// 507.517 us; speedup vs baseline: 2.5103x; 2.5103x over previous
//
#include <hip/hip_runtime.h>

typedef unsigned short ushort_t;
typedef __attribute__((ext_vector_type(8))) short short8;
typedef __attribute__((ext_vector_type(4))) float f32x4;

#define BB   2
#define CCH  256
#define HF   96
#define WF   320
#define NYC  7
#define DWT  16384          // 128*128
#define PLANE (HF*WF)       // 30720
#define KDIM (CCH*NYC)      // 1792
#define MBLK 32             // positions per block (MFMA path)
#define KC   224            // K-chunk = 32 channels * 7
#define KC_PAD 232          // padded LDS row (ushorts) to spread banks
#define NCHUNK 8
#define PPB  8              // positions per block (fallback path)

#define WBF_ELEMS (16*56*64*8)          // 458752 bf16
#define WBF_BYTES (WBF_ELEMS*2)         // 917504 B
#define IIT_BYTES ((size_t)BB*PLANE*CCH*4)

__device__ __forceinline__ ushort_t f2bf(float f) {
    unsigned u = __float_as_uint(f);
    u += 0x7fffu + ((u >> 16) & 1u);    // round-to-nearest-even
    return (ushort_t)(u >> 16);
}

// ---------------- K1: row cumsum (axis -1) ----------------
__global__ void k_rowcum(const float* __restrict__ f, float* __restrict__ ii) {
    int row = blockIdx.x * blockDim.x + threadIdx.x;
    if (row >= BB * CCH * HF) return;
    const float* src = f  + (size_t)row * WF;
    float*       dst = ii + (size_t)row * WF;
    float carry = 0.f;
    for (int i = 0; i < WF; i += 4) {
        float4 v = *reinterpret_cast<const float4*>(src + i);
        float a0 = carry + v.x;
        float a1 = a0 + v.y;
        float a2 = a1 + v.z;
        float a3 = a2 + v.w;
        *reinterpret_cast<float4*>(dst + i) = make_float4(a0, a1, a2, a3);
        carry = a3;
    }
}

// ---------------- K2: col cumsum (axis -2), in place ----------------
__global__ void k_colcum(float* __restrict__ ii) {
    int t = blockIdx.x * blockDim.x + threadIdx.x;
    if (t >= BB * CCH * WF) return;
    int x  = t % WF;
    int bc = t / WF;
    float* p = ii + (size_t)bc * PLANE + x;
    float acc = 0.f;
    for (int y = 0; y < HF; ++y) {
        acc += p[(size_t)y * WF];
        p[(size_t)y * WF] = acc;
    }
}

// ---------------- K3: transpose ii (B,C,H,W) -> ii_t (B,H,W,C) ----------------
__global__ void k_transpose(const float* __restrict__ ii, float* __restrict__ iit) {
    __shared__ float tile[32][33];
    int x0 = blockIdx.x * 32;
    int c0 = blockIdx.y * 32;
    int by = blockIdx.z;               // b*HF + y
    int b  = by / HF;
    int y  = by % HF;
    const float* src = ii  + (size_t)b * CCH * PLANE + (size_t)y * WF;
    float*       dst = iit + (size_t)by * WF * CCH;
    int tx = threadIdx.x;
    int ty = threadIdx.y;
    #pragma unroll
    for (int i = 0; i < 4; ++i) {
        int c = c0 + ty + 8 * i;
        tile[ty + 8 * i][tx] = src[(size_t)c * PLANE + x0 + tx];
    }
    __syncthreads();
    #pragma unroll
    for (int i = 0; i < 4; ++i) {
        int x = x0 + ty + 8 * i;
        dst[(size_t)x * CCH + c0 + tx] = tile[tx][ty + 8 * i];
    }
}

// ---------------- K4: geometry -> g_tl, g_br, g_tr, g_bl ----------------
__global__ void k_geom(const float* __restrict__ calib, const float* __restrict__ grid,
                       float* __restrict__ gtl, float* __restrict__ gbr,
                       float* __restrict__ gtr, float* __restrict__ gbl) {
    int t = blockIdx.x * blockDim.x + threadIdx.x;
    if (t >= BB * NYC * DWT) return;
    int dw = t % DWT;
    int by = t / DWT;
    int y  = by % NYC;
    int b  = by / NYC;
    int d  = dw >> 7;
    int w  = dw & 127;
    const float* cb = calib + b * 12;

    float c0=cb[0],c1=cb[1],c2=cb[2],c3=cb[3];
    float c4=cb[4],c5=cb[5],c6=cb[6],c7=cb[7];
    float c8=cb[8],c9=cb[9],c10=cb[10],c11=cb[11];

    auto ncp = [&](int yy, int i, int j, float& ox, float& oy) {
        const float* g = grid + (((size_t)b * 129 + i) * 129 + j) * 3;
        float gx = g[0];
        float gy = g[1] + (0.5f * (float)yy - 2.0f);
        float gz = g[2];
        float h0 = c0*gx + c1*gy + c2*gz + c3;
        float h1 = c4*gx + c5*gy + c6*gz + c7;
        float h2 = c8*gx + c9*gy + c10*gz + c11;
        float ix = h0 / h2;
        float iy = h1 / h2;
        float nx = 2.0f * ix / ((float)WF / 0.125f) - 1.0f;
        float ny = 2.0f * iy / ((float)HF / 0.125f) - 1.0f;
        ox = fminf(fmaxf(nx, -1.f), 1.f);
        oy = fminf(fmaxf(ny, -1.f), 1.f);
    };

    float ax, ay, bx, byy, mx1, my1, mx2, my2;
    ncp(y,     d,     w,     ax,  ay);
    ncp(y,     d + 1, w,     bx,  byy);
    float minx = fminf(ax, bx), miny = fminf(ay, byy);
    ncp(y + 1, d + 1, w + 1, mx1, my1);
    ncp(y + 1, d,     w + 1, mx2, my2);
    float maxx = fmaxf(mx1, mx2), maxy = fmaxf(my1, my2);

    size_t o = (size_t)t * 2;
    gtl[o] = minx; gtl[o + 1] = miny;
    gbr[o] = maxx; gbr[o + 1] = maxy;
    gtr[o] = maxx; gtr[o + 1] = miny;
    gbl[o] = minx; gbl[o + 1] = maxy;
}

// ---------------- K5a: prepack w (256,1792) f32 -> fragment-linear bf16 ------
// wbf[(((ntile*56 + ktile)*64 + lane)*8 + j] = bf16(w[ntile*16+(lane&15)][ktile*32+(lane>>4)*8+j])
__global__ void k_prepack(const float* __restrict__ w, ushort_t* __restrict__ wbf) {
    int t = blockIdx.x * blockDim.x + threadIdx.x;
    if (t >= 16 * 56 * 64) return;
    int lane = t & 63;
    int kt   = (t >> 6) % 56;
    int nt   = t / (56 * 64);
    const float* src = w + (size_t)(nt * 16 + (lane & 15)) * KDIM + kt * 32 + (lane >> 4) * 8;
    ushort_t* dst = wbf + (size_t)t * 8;
    #pragma unroll
    for (int j = 0; j < 8; ++j) dst[j] = f2bf(src[j]);
}

// ---------------- K5b: fused sample -> bf16 A-tile -> MFMA GEMM --------------
__global__ __launch_bounds__(256)
void k_mfma(const float* __restrict__ iit, const ushort_t* __restrict__ wbf,
            const float* __restrict__ gtl, const float* __restrict__ gbr,
            const float* __restrict__ bias, float* __restrict__ ortho) {
    __shared__ ushort_t A[MBLK][KC_PAD];       // 14848 B
    __shared__ int2 taps[MBLK][NYC][16];       // 28672 B

    int t   = threadIdx.x;
    // XCD-chunked swizzle (nwg=1024, divisible by 8): contiguous dw per XCD
    int bid = blockIdx.x;
    int cpx = gridDim.x >> 3;
    int swz = (bid & 7) * cpx + (bid >> 3);
    int pos0 = swz * MBLK;
    int b   = pos0 / DWT;
    int dw0 = pos0 % DWT;

    // ---- build tap tables (idx, weight) ----
    if (t < MBLK * NYC) {
        int p = t / NYC, y = t % NYC;
        size_t gi = (((size_t)(b * NYC + y)) * DWT + dw0 + p) * 2;
        float g0 = gtl[gi], g1 = gtl[gi + 1];
        float g2 = gbr[gi], g3 = gbr[gi + 1];
        float area = (g2 - g0) * (g3 - g1) * ((float)HF * (float)WF * 0.25f) + 1e-6f;
        float inv  = (area > 1e-6f) ? (1.0f / area) : 0.0f;
        const float sgn[4] = {1.f, 1.f, -1.f, -1.f};
        float px[4] = {g0, g2, g2, g0};
        float py[4] = {g1, g3, g1, g3};
        #pragma unroll
        for (int q = 0; q < 4; ++q) {
            float x  = (px[q] + 1.0f) * ((float)WF * 0.5f) - 0.5f;
            float yy = (py[q] + 1.0f) * ((float)HF * 0.5f) - 0.5f;
            float x0f = floorf(x), y0f = floorf(yy);
            float wx = x - x0f, wy = yy - y0f;
            float wq[4] = {(1.f-wx)*(1.f-wy), wx*(1.f-wy), (1.f-wx)*wy, wx*wy};
            #pragma unroll
            for (int s = 0; s < 4; ++s) {
                float xi = x0f + (float)(s & 1);
                float yi = y0f + (float)(s >> 1);
                bool valid = (xi >= 0.f) && (xi < (float)WF) && (yi >= 0.f) && (yi < (float)HF);
                int xc = (int)fminf(fmaxf(xi, 0.f), (float)(WF - 1));
                int yc = (int)fminf(fmaxf(yi, 0.f), (float)(HF - 1));
                taps[p][y][q * 4 + s] =
                    make_int2(yc * WF + xc, __float_as_int(valid ? (wq[s] * sgn[q] * inv) : 0.0f));
            }
        }
    }
    __syncthreads();

    int lane = t & 63, wid = t >> 6;
    int n0   = wid * 64;                 // this wave's output-channel base
    f32x4 acc[2][4] = {};                // M 2x16 , N 4x16

    int p   = t >> 3;                    // position 0..31
    int ch4 = (t & 7) * 4;               // 4 channels within the 32-ch chunk
    const float* base0 = iit + (size_t)b * PLANE * CCH;

    for (int kc = 0; kc < NCHUNK; ++kc) {
        // ---- phase 1: sample 32 channels of this chunk into A (bf16) ----
        const float* base = base0 + kc * 32 + ch4;
        float av[4][NYC];
        for (int y = 0; y < NYC; ++y) {
            float sx = 0.f, sy = 0.f, sz = 0.f, sw = 0.f;
            #pragma unroll
            for (int q = 0; q < 16; ++q) {
                int2 tp = taps[p][y][q];
                float wg = __int_as_float(tp.y);
                float4 v = *reinterpret_cast<const float4*>(base + (size_t)tp.x * CCH);
                sx += wg * v.x; sy += wg * v.y; sz += wg * v.z; sw += wg * v.w;
            }
            av[0][y] = sx; av[1][y] = sy; av[2][y] = sz; av[3][y] = sw;
        }
        #pragma unroll
        for (int i = 0; i < 4; ++i) {
            ushort_t* row = &A[p][(ch4 + i) * NYC];
            #pragma unroll
            for (int y = 0; y < NYC; ++y) row[y] = f2bf(av[i][y]);
        }
        __syncthreads();

        // ---- phase 2: MFMA over this K-chunk ----
        int r = lane & 15, g = lane >> 4;
        #pragma unroll
        for (int kt = 0; kt < 7; ++kt) {
            short8 a0 = *reinterpret_cast<const short8*>(&A[r][kt * 32 + g * 8]);
            short8 a1 = *reinterpret_cast<const short8*>(&A[16 + r][kt * 32 + g * 8]);
            int ktile = kc * 7 + kt;
            #pragma unroll
            for (int nt = 0; nt < 4; ++nt) {
                short8 bf = *reinterpret_cast<const short8*>(
                    wbf + ((((size_t)(wid * 4 + nt)) * 56 + ktile) * 64 + lane) * 8);
                acc[0][nt] = __builtin_amdgcn_mfma_f32_16x16x32_bf16(a0, bf, acc[0][nt], 0, 0, 0);
                acc[1][nt] = __builtin_amdgcn_mfma_f32_16x16x32_bf16(a1, bf, acc[1][nt], 0, 0, 0);
            }
        }
        __syncthreads();
    }

    // ---- epilogue: bias + relu + float4 stores (4 contiguous positions/lane) ----
    int r = lane & 15, g = lane >> 4;
    #pragma unroll
    for (int nt = 0; nt < 4; ++nt) {
        int co = n0 + nt * 16 + r;
        float bv = bias[co];
        float* obase = ortho + ((size_t)(b * CCH + co)) * DWT + dw0;
        #pragma unroll
        for (int m = 0; m < 2; ++m) {
            int pos = m * 16 + g * 4;
            float4 o = make_float4(fmaxf(acc[m][nt][0] + bv, 0.f),
                                   fmaxf(acc[m][nt][1] + bv, 0.f),
                                   fmaxf(acc[m][nt][2] + bv, 0.f),
                                   fmaxf(acc[m][nt][3] + bv, 0.f));
            *reinterpret_cast<float4*>(obase + pos) = o;
        }
    }
}

// ---------------- fallback: round-1 fused kernel (slow but ws-independent) ----
__global__ __launch_bounds__(256)
void k_sample_mm_slow(const float* __restrict__ iisrc,
                      const float* __restrict__ gtl, const float* __restrict__ gbr,
                      const float* __restrict__ w, const float* __restrict__ bias,
                      float* __restrict__ ortho) {
    __shared__ float vox[PPB][KDIM];
    __shared__ int   tidx[PPB][NYC][16];
    __shared__ float twgt[PPB][NYC][16];

    int t   = threadIdx.x;
    int pg0 = blockIdx.x * PPB;
    int b   = pg0 / DWT;
    int dw0 = pg0 % DWT;

    if (t < PPB * NYC) {
        int p = t / NYC, y = t % NYC;
        size_t gi = (((size_t)(b * NYC + y)) * DWT + dw0 + p) * 2;
        float g0 = gtl[gi], g1 = gtl[gi + 1];
        float g2 = gbr[gi], g3 = gbr[gi + 1];
        float area = (g2 - g0) * (g3 - g1) * ((float)HF * (float)WF * 0.25f) + 1e-6f;
        float inv  = (area > 1e-6f) ? (1.0f / area) : 0.0f;
        const float sgn[4] = {1.f, 1.f, -1.f, -1.f};
        float px[4] = {g0, g2, g2, g0};
        float py[4] = {g1, g3, g1, g3};
        #pragma unroll
        for (int q = 0; q < 4; ++q) {
            float x  = (px[q] + 1.0f) * ((float)WF * 0.5f) - 0.5f;
            float yy = (py[q] + 1.0f) * ((float)HF * 0.5f) - 0.5f;
            float x0f = floorf(x), y0f = floorf(yy);
            float wx = x - x0f, wy = yy - y0f;
            float wq[4] = {(1.f-wx)*(1.f-wy), wx*(1.f-wy), (1.f-wx)*wy, wx*wy};
            #pragma unroll
            for (int s = 0; s < 4; ++s) {
                float xi = x0f + (float)(s & 1);
                float yi = y0f + (float)(s >> 1);
                bool valid = (xi >= 0.f) && (xi < (float)WF) && (yi >= 0.f) && (yi < (float)HF);
                int xc = (int)fminf(fmaxf(xi, 0.f), (float)(WF - 1));
                int yc = (int)fminf(fmaxf(yi, 0.f), (float)(HF - 1));
                tidx[p][y][q * 4 + s] = yc * WF + xc;
                twgt[p][y][q * 4 + s] = valid ? (wq[s] * sgn[q] * inv) : 0.0f;
            }
        }
    }
    __syncthreads();

    {
        int c = t;
        const float* base = iisrc + ((size_t)(b * CCH + c)) * PLANE;
        for (int p = 0; p < PPB; ++p) {
            #pragma unroll
            for (int y = 0; y < NYC; ++y) {
                float acc = 0.f;
                #pragma unroll
                for (int s = 0; s < 16; ++s) {
                    acc += twgt[p][y][s] * base[tidx[p][y][s]];
                }
                vox[p][c * NYC + y] = acc;
            }
        }
    }
    __syncthreads();

    int co = t;
    float acc[PPB];
    float bv = bias[co];
    #pragma unroll
    for (int p = 0; p < PPB; ++p) acc[p] = bv;

    const float4* wrow = reinterpret_cast<const float4*>(w + (size_t)co * KDIM);
    for (int k4 = 0; k4 < KDIM / 4; ++k4) {
        float4 wv = wrow[k4];
        #pragma unroll
        for (int p = 0; p < PPB; ++p) {
            float4 vv = *reinterpret_cast<const float4*>(&vox[p][k4 * 4]);
            acc[p] += vv.x * wv.x + vv.y * wv.y + vv.z * wv.z + vv.w * wv.w;
        }
    }

    float* orow = ortho + ((size_t)(b * CCH + co)) * DWT + dw0;
    float4 o0 = make_float4(fmaxf(acc[0], 0.f), fmaxf(acc[1], 0.f),
                            fmaxf(acc[2], 0.f), fmaxf(acc[3], 0.f));
    float4 o1 = make_float4(fmaxf(acc[4], 0.f), fmaxf(acc[5], 0.f),
                            fmaxf(acc[6], 0.f), fmaxf(acc[7], 0.f));
    *reinterpret_cast<float4*>(orow)     = o0;
    *reinterpret_cast<float4*>(orow + 4) = o1;
}

extern "C" void kernel_launch(void* const* d_in, const int* in_sizes, int n_in,
                              void* d_out, int out_size, void* d_ws, size_t ws_size,
                              hipStream_t stream) {
    const float* features = (const float*)d_in[0];
    const float* calib    = (const float*)d_in[1];
    const float* grid     = (const float*)d_in[2];
    const float* w        = (const float*)d_in[3];
    const float* bias     = (const float*)d_in[4];

    float* out   = (float*)d_out;
    float* ortho = out;
    float* ii    = out + (size_t)8388608;
    float* gtl   = out + (size_t)24117248;
    float* gbr   = out + (size_t)24576000;
    float* gtr   = out + (size_t)25034752;
    float* gbl   = out + (size_t)25493504;

    ushort_t* wbf = (ushort_t*)d_ws;
    float*    iit = (float*)((char*)d_ws + WBF_BYTES);
    bool fast = (ws_size >= WBF_BYTES + IIT_BYTES);

    k_rowcum<<<(BB * CCH * HF + 255) / 256, 256, 0, stream>>>(features, ii);
    k_colcum<<<(BB * CCH * WF + 255) / 256, 256, 0, stream>>>(ii);
    k_geom  <<<(BB * NYC * DWT + 255) / 256, 256, 0, stream>>>(calib, grid, gtl, gbr, gtr, gbl);

    if (fast) {
        k_prepack<<<(16 * 56 * 64 + 255) / 256, 256, 0, stream>>>(w, wbf);
        dim3 gT(WF / 32, CCH / 32, BB * HF);
        k_transpose<<<gT, dim3(32, 8), 0, stream>>>(ii, iit);
        k_mfma<<<BB * DWT / MBLK, 256, 0, stream>>>(iit, wbf, gtl, gbr, bias, ortho);
    } else {
        k_sample_mm_slow<<<BB * DWT / PPB, 256, 0, stream>>>(ii, gtl, gbr, w, bias, ortho);
    }
}

// Round 3
// 261.291 us; speedup vs baseline: 4.8759x; 1.9423x over previous
//
#include <hip/hip_runtime.h>
#include <hip/hip_fp16.h>

typedef unsigned short ushort_t;
typedef __attribute__((ext_vector_type(8))) short short8;
typedef __attribute__((ext_vector_type(4))) float f32x4;

#define BB   2
#define CCH  256
#define HF   96
#define WF   320
#define NYC  7
#define DWT  16384
#define PLANE (HF*WF)          // 30720
#define KDIM (CCH*NYC)         // 1792
#define NKT  56                // K tiles of 32 (K = 1792)
#define MS   8                 // positions per sample block
#define GM   32                // positions per gemm block
#define POS_TOTAL (BB*DWT)     // 32768

#define WBF_BYTES  ((size_t)16*NKT*64*8*2)          // 917504
#define IITH_BYTES ((size_t)BB*PLANE*CCH*2)         // 31457280

__device__ __forceinline__ ushort_t f2bf(float f) {
    unsigned u = __float_as_uint(f);
    u += 0x7fffu + ((u >> 16) & 1u);
    return (ushort_t)(u >> 16);
}

// ---------------- K1: row cumsum ----------------
__global__ void k_rowcum(const float* __restrict__ f, float* __restrict__ ii) {
    int row = blockIdx.x * blockDim.x + threadIdx.x;
    if (row >= BB * CCH * HF) return;
    const float* src = f  + (size_t)row * WF;
    float*       dst = ii + (size_t)row * WF;
    float carry = 0.f;
    for (int i = 0; i < WF; i += 4) {
        float4 v = *reinterpret_cast<const float4*>(src + i);
        float a0 = carry + v.x;
        float a1 = a0 + v.y;
        float a2 = a1 + v.z;
        float a3 = a2 + v.w;
        *reinterpret_cast<float4*>(dst + i) = make_float4(a0, a1, a2, a3);
        carry = a3;
    }
}

// ---------------- K2: col cumsum, in place ----------------
__global__ void k_colcum(float* __restrict__ ii) {
    int t = blockIdx.x * blockDim.x + threadIdx.x;
    if (t >= BB * CCH * WF) return;
    int x  = t % WF;
    int bc = t / WF;
    float* p = ii + (size_t)bc * PLANE + x;
    float acc = 0.f;
    for (int y = 0; y < HF; ++y) {
        acc += p[(size_t)y * WF];
        p[(size_t)y * WF] = acc;
    }
}

// ---------------- K3: transpose ii (B,C,H,W) f32 -> iith (B,H,W,C) fp16 ------
__global__ void k_transpose(const float* __restrict__ ii, _Float16* __restrict__ iith) {
    __shared__ float tile[32][33];
    int x0 = blockIdx.x * 32;
    int c0 = blockIdx.y * 32;
    int by = blockIdx.z;               // b*HF + y
    int b  = by / HF;
    int y  = by % HF;
    const float* src = ii + (size_t)b * CCH * PLANE + (size_t)y * WF;
    unsigned* dstu = reinterpret_cast<unsigned*>(iith + (size_t)by * WF * CCH);
    int tx = threadIdx.x;              // 0..31
    int ty = threadIdx.y;              // 0..7
    #pragma unroll
    for (int i = 0; i < 4; ++i) {
        int c = c0 + ty + 8 * i;
        tile[ty + 8 * i][tx] = src[(size_t)c * PLANE + x0 + tx];
    }
    __syncthreads();
    int id = ty * 32 + tx;             // 0..255
    #pragma unroll
    for (int it = 0; it < 2; ++it) {
        int idx = it * 256 + id;       // 0..511 -> (xl 0..31, j 0..15)
        int xl = idx >> 4;
        int j  = idx & 15;
        float f0 = tile[2 * j][xl];
        float f1 = tile[2 * j + 1][xl];
        __half2 hh = __floats2half2_rn(f0, f1);
        dstu[((size_t)(x0 + xl) * CCH + c0) / 2 + j] = *reinterpret_cast<unsigned*>(&hh);
    }
}

// ---------------- K4: geometry -> g_tl, g_br, g_tr, g_bl ----------------
__global__ void k_geom(const float* __restrict__ calib, const float* __restrict__ grid,
                       float* __restrict__ gtl, float* __restrict__ gbr,
                       float* __restrict__ gtr, float* __restrict__ gbl) {
    int t = blockIdx.x * blockDim.x + threadIdx.x;
    if (t >= BB * NYC * DWT) return;
    int dw = t % DWT;
    int by = t / DWT;
    int y  = by % NYC;
    int b  = by / NYC;
    int d  = dw >> 7;
    int w  = dw & 127;
    const float* cb = calib + b * 12;

    float c0=cb[0],c1=cb[1],c2=cb[2],c3=cb[3];
    float c4=cb[4],c5=cb[5],c6=cb[6],c7=cb[7];
    float c8=cb[8],c9=cb[9],c10=cb[10],c11=cb[11];

    auto ncp = [&](int yy, int i, int j, float& ox, float& oy) {
        const float* g = grid + (((size_t)b * 129 + i) * 129 + j) * 3;
        float gx = g[0];
        float gy = g[1] + (0.5f * (float)yy - 2.0f);
        float gz = g[2];
        float h0 = c0*gx + c1*gy + c2*gz + c3;
        float h1 = c4*gx + c5*gy + c6*gz + c7;
        float h2 = c8*gx + c9*gy + c10*gz + c11;
        float ix = h0 / h2;
        float iy = h1 / h2;
        float nx = 2.0f * ix / ((float)WF / 0.125f) - 1.0f;
        float ny = 2.0f * iy / ((float)HF / 0.125f) - 1.0f;
        ox = fminf(fmaxf(nx, -1.f), 1.f);
        oy = fminf(fmaxf(ny, -1.f), 1.f);
    };

    float ax, ay, bx, byy, mx1, my1, mx2, my2;
    ncp(y,     d,     w,     ax,  ay);
    ncp(y,     d + 1, w,     bx,  byy);
    float minx = fminf(ax, bx), miny = fminf(ay, byy);
    ncp(y + 1, d + 1, w + 1, mx1, my1);
    ncp(y + 1, d,     w + 1, mx2, my2);
    float maxx = fmaxf(mx1, mx2), maxy = fmaxf(my1, my2);

    size_t o = (size_t)t * 2;
    gtl[o] = minx; gtl[o + 1] = miny;
    gbr[o] = maxx; gbr[o + 1] = maxy;
    gtr[o] = maxx; gtr[o + 1] = miny;
    gbl[o] = minx; gbl[o + 1] = maxy;
}

// ---------------- K5: prepack w -> fragment-linear bf16 (K-order k=y*256+c) --
__global__ void k_prepack(const float* __restrict__ w, ushort_t* __restrict__ wbf) {
    int t = blockIdx.x * blockDim.x + threadIdx.x;
    if (t >= 16 * NKT * 64) return;
    int lane = t & 63;
    int kt   = (t >> 6) % NKT;
    int nt   = t / (NKT * 64);
    int r = lane & 15, g = lane >> 4;
    const float* wr = w + (size_t)(nt * 16 + r) * KDIM;
    ushort_t* dst = wbf + (size_t)t * 8;
    #pragma unroll
    for (int j = 0; j < 8; ++j) {
        int k  = kt * 32 + g * 8 + j;
        int yy = k >> 8;
        int cc = k & 255;
        dst[j] = f2bf(wr[cc * NYC + yy]);
    }
}

// ---------------- K6: pure gather -> vox fragments (bf16) --------------------
// thread: p = t>>5 (8 positions/block), c = (t&31)*8 (channel octet)
__global__ __launch_bounds__(256)
void k_sample(const _Float16* __restrict__ iith, const float* __restrict__ gtl,
              const float* __restrict__ gbr, ushort_t* __restrict__ voxf, int pos_base) {
    __shared__ int2 taps[MS][NYC][16];
    int t = threadIdx.x;
    int bid = blockIdx.x;
    int cpx = gridDim.x >> 3;
    int swz = (bid & 7) * cpx + (bid >> 3);     // XCD-chunked (grid % 8 == 0)
    int lpos0 = swz * MS;
    int pos0  = pos_base + lpos0;
    int b   = pos0 / DWT;
    int dw0 = pos0 % DWT;

    if (t < MS * NYC) {
        int p = t / NYC, y = t % NYC;
        size_t gi = (((size_t)(b * NYC + y)) * DWT + dw0 + p) * 2;
        float g0 = gtl[gi], g1 = gtl[gi + 1];
        float g2 = gbr[gi], g3 = gbr[gi + 1];
        float area = (g2 - g0) * (g3 - g1) * ((float)HF * (float)WF * 0.25f) + 1e-6f;
        float inv  = (area > 1e-6f) ? (1.0f / area) : 0.0f;
        const float sgn[4] = {1.f, 1.f, -1.f, -1.f};
        float px[4] = {g0, g2, g2, g0};
        float py[4] = {g1, g3, g1, g3};
        #pragma unroll
        for (int q = 0; q < 4; ++q) {
            float x  = (px[q] + 1.0f) * ((float)WF * 0.5f) - 0.5f;
            float yy = (py[q] + 1.0f) * ((float)HF * 0.5f) - 0.5f;
            float x0f = floorf(x), y0f = floorf(yy);
            float wx = x - x0f, wy = yy - y0f;
            float wq[4] = {(1.f-wx)*(1.f-wy), wx*(1.f-wy), (1.f-wx)*wy, wx*wy};
            #pragma unroll
            for (int s = 0; s < 4; ++s) {
                float xi = x0f + (float)(s & 1);
                float yi = y0f + (float)(s >> 1);
                bool valid = (xi >= 0.f) && (xi < (float)WF) && (yi >= 0.f) && (yi < (float)HF);
                int xc = (int)fminf(fmaxf(xi, 0.f), (float)(WF - 1));
                int yc = (int)fminf(fmaxf(yi, 0.f), (float)(HF - 1));
                taps[p][y][q * 4 + s] =
                    make_int2(yc * WF + xc, __float_as_int(valid ? (wq[s] * sgn[q] * inv) : 0.0f));
            }
        }
    }
    __syncthreads();

    int p = t >> 5;
    int c = (t & 31) * 8;
    int lpos = lpos0 + p;
    int mt = lpos >> 4, r = lpos & 15, g = (c >> 3) & 3;
    const _Float16* base = iith + (size_t)b * PLANE * CCH + c;
    ushort_t* vbase = voxf + ((size_t)mt * NKT * 64 + (size_t)(g * 16 + r)) * 8;

    for (int y = 0; y < NYC; ++y) {
        float acc[8] = {0.f,0.f,0.f,0.f,0.f,0.f,0.f,0.f};
        #pragma unroll
        for (int q = 0; q < 16; ++q) {
            int2 tp = taps[p][y][q];
            float wg = __int_as_float(tp.y);
            uint4 hv = *reinterpret_cast<const uint4*>(base + (size_t)tp.x * CCH);
            float2 f;
            f = __half22float2(*reinterpret_cast<__half2*>(&hv.x)); acc[0] += wg*f.x; acc[1] += wg*f.y;
            f = __half22float2(*reinterpret_cast<__half2*>(&hv.y)); acc[2] += wg*f.x; acc[3] += wg*f.y;
            f = __half22float2(*reinterpret_cast<__half2*>(&hv.z)); acc[4] += wg*f.x; acc[5] += wg*f.y;
            f = __half22float2(*reinterpret_cast<__half2*>(&hv.w)); acc[6] += wg*f.x; acc[7] += wg*f.y;
        }
        int kt = (y << 3) + (c >> 5);
        short8 o;
        #pragma unroll
        for (int j = 0; j < 8; ++j) o[j] = (short)f2bf(acc[j]);
        *reinterpret_cast<short8*>(vbase + (size_t)kt * 64 * 8) = o;
    }
}

// ---------------- K7: fragment-direct MFMA GEMM (M=GM, N=256 per block) ------
// 8 waves: mi = wv>>2 (m-frag), ni = wv&3 (N 64-chunk). No LDS.
__global__ __launch_bounds__(512)
void k_gemm(const ushort_t* __restrict__ voxf, const ushort_t* __restrict__ wbf,
            const float* __restrict__ bias, float* __restrict__ ortho, int pos_base) {
    int t = threadIdx.x;
    int lane = t & 63, wv = t >> 6;
    int mi = wv >> 2, ni = wv & 3;
    int lpos0 = blockIdx.x * GM;
    int mt = (lpos0 >> 4) + mi;
    int pos0 = pos_base + lpos0;
    int b = pos0 / DWT, dw0 = pos0 % DWT;

    const short8* ap = reinterpret_cast<const short8*>(voxf) + ((size_t)mt * NKT * 64 + lane);
    const short8* bp = reinterpret_cast<const short8*>(wbf) + ((size_t)(ni * 4) * NKT * 64 + lane);

    f32x4 acc[4] = {};
    short8 a = ap[0];
    short8 bc[4];
    #pragma unroll
    for (int nt = 0; nt < 4; ++nt) bc[nt] = bp[(size_t)nt * NKT * 64];

    for (int kt = 0; kt < NKT - 1; ++kt) {
        short8 an = ap[(size_t)(kt + 1) * 64];
        short8 bn[4];
        #pragma unroll
        for (int nt = 0; nt < 4; ++nt) bn[nt] = bp[(size_t)nt * NKT * 64 + (size_t)(kt + 1) * 64];
        #pragma unroll
        for (int nt = 0; nt < 4; ++nt)
            acc[nt] = __builtin_amdgcn_mfma_f32_16x16x32_bf16(a, bc[nt], acc[nt], 0, 0, 0);
        a = an;
        #pragma unroll
        for (int nt = 0; nt < 4; ++nt) bc[nt] = bn[nt];
    }
    #pragma unroll
    for (int nt = 0; nt < 4; ++nt)
        acc[nt] = __builtin_amdgcn_mfma_f32_16x16x32_bf16(a, bc[nt], acc[nt], 0, 0, 0);

    int r = lane & 15, gq = lane >> 4;
    #pragma unroll
    for (int nt = 0; nt < 4; ++nt) {
        int co = ni * 64 + nt * 16 + r;
        float bv = bias[co];
        float* obase = ortho + ((size_t)(b * CCH + co)) * DWT + dw0 + mi * 16 + gq * 4;
        float4 o = make_float4(fmaxf(acc[nt][0] + bv, 0.f), fmaxf(acc[nt][1] + bv, 0.f),
                               fmaxf(acc[nt][2] + bv, 0.f), fmaxf(acc[nt][3] + bv, 0.f));
        *reinterpret_cast<float4*>(obase) = o;
    }
}

extern "C" void kernel_launch(void* const* d_in, const int* in_sizes, int n_in,
                              void* d_out, int out_size, void* d_ws, size_t ws_size,
                              hipStream_t stream) {
    const float* features = (const float*)d_in[0];
    const float* calib    = (const float*)d_in[1];
    const float* grid     = (const float*)d_in[2];
    const float* w        = (const float*)d_in[3];
    const float* bias     = (const float*)d_in[4];

    float* out   = (float*)d_out;
    float* ortho = out;
    float* ii    = out + (size_t)8388608;
    float* gtl   = out + (size_t)24117248;
    float* gbr   = out + (size_t)24576000;
    float* gtr   = out + (size_t)25034752;
    float* gbl   = out + (size_t)25493504;

    ushort_t* wbf  = (ushort_t*)d_ws;
    _Float16* iith = (_Float16*)((char*)d_ws + WBF_BYTES);
    ushort_t* voxf = (ushort_t*)((char*)d_ws + WBF_BYTES + IITH_BYTES);

    k_rowcum<<<(BB * CCH * HF + 255) / 256, 256, 0, stream>>>(features, ii);
    k_colcum<<<(BB * CCH * WF + 255) / 256, 256, 0, stream>>>(ii);
    k_geom  <<<(BB * NYC * DWT + 255) / 256, 256, 0, stream>>>(calib, grid, gtl, gbr, gtr, gbl);
    k_prepack<<<(16 * NKT * 64 + 255) / 256, 256, 0, stream>>>(w, wbf);
    dim3 gT(WF / 32, CCH / 32, BB * HF);
    k_transpose<<<gT, dim3(32, 8), 0, stream>>>(ii, iith);

    size_t vox_all = (size_t)POS_TOTAL * KDIM * 2;             // 117 MB
    int nch = (ws_size >= WBF_BYTES + IITH_BYTES + vox_all) ? 1 : 4;
    int cpos = POS_TOTAL / nch;
    for (int cidx = 0; cidx < nch; ++cidx) {
        int pb = cidx * cpos;
        k_sample<<<cpos / MS, 256, 0, stream>>>(iith, gtl, gbr, voxf, pb);
        k_gemm  <<<cpos / GM, 512, 0, stream>>>(voxf, wbf, bias, ortho, pb);
    }
}

// Round 4
// 178.982 us; speedup vs baseline: 7.1182x; 1.4599x over previous
//
#include <hip/hip_runtime.h>
#include <hip/hip_fp16.h>

typedef unsigned short ushort_t;
typedef __attribute__((ext_vector_type(8))) short short8;
typedef __attribute__((ext_vector_type(4))) float f32x4;

#define BB   2
#define CCH  256
#define HF   96
#define WF   320
#define NYC  7
#define DWT  16384
#define PLANE (HF*WF)          // 30720
#define KDIM (CCH*NYC)         // 1792
#define NKT  56                // K tiles of 32
#define MS   8                 // positions per sample block
#define POS_TOTAL (BB*DWT)     // 32768

#define WBF_BYTES  ((size_t)16*NKT*64*8*2)          // 917504
#define IITH_BYTES ((size_t)BB*PLANE*CCH*2)         // 31457280

__device__ __forceinline__ ushort_t f2bf(float f) {
    unsigned u = __float_as_uint(f);
    u += 0x7fffu + ((u >> 16) & 1u);
    return (ushort_t)(u >> 16);
}

// ---------------- K1: fused integral image (rowcum + colcum) -----------------
// one block per (b,c) plane; plane staged in LDS (120 KB)
__global__ __launch_bounds__(512)
void k_integral(const float* __restrict__ f, float* __restrict__ ii) {
    __shared__ float pl[PLANE];            // 122880 B
    int bc = blockIdx.x;
    const float* src = f  + (size_t)bc * PLANE;
    float*       dst = ii + (size_t)bc * PLANE;
    int t = threadIdx.x;

    // load plane (float4, coalesced)
    #pragma unroll
    for (int i = 0; i < PLANE / 4 / 512; ++i) {
        int idx = t + i * 512;
        reinterpret_cast<float4*>(pl)[idx] = reinterpret_cast<const float4*>(src)[idx];
    }
    __syncthreads();

    // row scan: 8 waves x 12 rows, 5 elems/lane + wave inclusive scan
    int lane = t & 63, wv = t >> 6;
    for (int rr = 0; rr < 12; ++rr) {
        float* row = &pl[(wv * 12 + rr) * WF];
        float v0 = row[lane * 5 + 0];
        float v1 = row[lane * 5 + 1];
        float v2 = row[lane * 5 + 2];
        float v3 = row[lane * 5 + 3];
        float v4 = row[lane * 5 + 4];
        v1 += v0; v2 += v1; v3 += v2; v4 += v3;
        float s = v4;
        #pragma unroll
        for (int d = 1; d < 64; d <<= 1) {
            float o = __shfl_up(s, d);
            if (lane >= d) s += o;
        }
        float pre = s - v4;
        row[lane * 5 + 0] = v0 + pre;
        row[lane * 5 + 1] = v1 + pre;
        row[lane * 5 + 2] = v2 + pre;
        row[lane * 5 + 3] = v3 + pre;
        row[lane * 5 + 4] = v4 + pre;
    }
    __syncthreads();

    // col scan + store to global (coalesced over x)
    if (t < WF) {
        int x = t;
        float acc = 0.f;
        #pragma unroll 4
        for (int y = 0; y < HF; ++y) {
            acc += pl[y * WF + x];
            dst[(size_t)y * WF + x] = acc;
        }
    }
}

// ---------------- K3: transpose ii (B,C,H,W) f32 -> iith (B,H,W,C) fp16 ------
__global__ void k_transpose(const float* __restrict__ ii, _Float16* __restrict__ iith) {
    __shared__ float tile[32][33];
    int x0 = blockIdx.x * 32;
    int c0 = blockIdx.y * 32;
    int by = blockIdx.z;               // b*HF + y
    int b  = by / HF;
    int y  = by % HF;
    const float* src = ii + (size_t)b * CCH * PLANE + (size_t)y * WF;
    unsigned* dstu = reinterpret_cast<unsigned*>(iith + (size_t)by * WF * CCH);
    int tx = threadIdx.x;
    int ty = threadIdx.y;
    #pragma unroll
    for (int i = 0; i < 4; ++i) {
        int c = c0 + ty + 8 * i;
        tile[ty + 8 * i][tx] = src[(size_t)c * PLANE + x0 + tx];
    }
    __syncthreads();
    int id = ty * 32 + tx;
    #pragma unroll
    for (int it = 0; it < 2; ++it) {
        int idx = it * 256 + id;
        int xl = idx >> 4;
        int j  = idx & 15;
        float f0 = tile[2 * j][xl];
        float f1 = tile[2 * j + 1][xl];
        __half2 hh = __floats2half2_rn(f0, f1);
        dstu[((size_t)(x0 + xl) * CCH + c0) / 2 + j] = *reinterpret_cast<unsigned*>(&hh);
    }
}

// ---------------- K4: geometry -> g_tl, g_br, g_tr, g_bl ----------------
__global__ void k_geom(const float* __restrict__ calib, const float* __restrict__ grid,
                       float* __restrict__ gtl, float* __restrict__ gbr,
                       float* __restrict__ gtr, float* __restrict__ gbl) {
    int t = blockIdx.x * blockDim.x + threadIdx.x;
    if (t >= BB * NYC * DWT) return;
    int dw = t % DWT;
    int by = t / DWT;
    int y  = by % NYC;
    int b  = by / NYC;
    int d  = dw >> 7;
    int w  = dw & 127;
    const float* cb = calib + b * 12;

    float c0=cb[0],c1=cb[1],c2=cb[2],c3=cb[3];
    float c4=cb[4],c5=cb[5],c6=cb[6],c7=cb[7];
    float c8=cb[8],c9=cb[9],c10=cb[10],c11=cb[11];

    auto ncp = [&](int yy, int i, int j, float& ox, float& oy) {
        const float* g = grid + (((size_t)b * 129 + i) * 129 + j) * 3;
        float gx = g[0];
        float gy = g[1] + (0.5f * (float)yy - 2.0f);
        float gz = g[2];
        float h0 = c0*gx + c1*gy + c2*gz + c3;
        float h1 = c4*gx + c5*gy + c6*gz + c7;
        float h2 = c8*gx + c9*gy + c10*gz + c11;
        float ix = h0 / h2;
        float iy = h1 / h2;
        float nx = 2.0f * ix / ((float)WF / 0.125f) - 1.0f;
        float ny = 2.0f * iy / ((float)HF / 0.125f) - 1.0f;
        ox = fminf(fmaxf(nx, -1.f), 1.f);
        oy = fminf(fmaxf(ny, -1.f), 1.f);
    };

    float ax, ay, bx, byy, mx1, my1, mx2, my2;
    ncp(y,     d,     w,     ax,  ay);
    ncp(y,     d + 1, w,     bx,  byy);
    float minx = fminf(ax, bx), miny = fminf(ay, byy);
    ncp(y + 1, d + 1, w + 1, mx1, my1);
    ncp(y + 1, d,     w + 1, mx2, my2);
    float maxx = fmaxf(mx1, mx2), maxy = fmaxf(my1, my2);

    size_t o = (size_t)t * 2;
    gtl[o] = minx; gtl[o + 1] = miny;
    gbr[o] = maxx; gbr[o + 1] = maxy;
    gtr[o] = maxx; gtr[o + 1] = miny;
    gbl[o] = minx; gbl[o + 1] = maxy;
}

// ---------------- K5: prepack w -> fragment-linear bf16 (k = y*256 + c) ------
__global__ void k_prepack(const float* __restrict__ w, ushort_t* __restrict__ wbf) {
    int t = blockIdx.x * blockDim.x + threadIdx.x;
    if (t >= 16 * NKT * 64) return;
    int lane = t & 63;
    int kt   = (t >> 6) % NKT;
    int nt   = t / (NKT * 64);
    int r = lane & 15, g = lane >> 4;
    const float* wr = w + (size_t)(nt * 16 + r) * KDIM;
    ushort_t* dst = wbf + (size_t)t * 8;
    #pragma unroll
    for (int j = 0; j < 8; ++j) {
        int k  = kt * 32 + g * 8 + j;
        int yy = k >> 8;
        int cc = k & 255;
        dst[j] = f2bf(wr[cc * NYC + yy]);
    }
}

// ---------------- K6: pure gather -> vox fragments (bf16) --------------------
__global__ __launch_bounds__(256)
void k_sample(const _Float16* __restrict__ iith, const float* __restrict__ gtl,
              const float* __restrict__ gbr, ushort_t* __restrict__ voxf, int pos_base) {
    __shared__ int2 taps[MS][NYC][16];
    int t = threadIdx.x;
    int bid = blockIdx.x;
    int cpx = gridDim.x >> 3;
    int swz = (bid & 7) * cpx + (bid >> 3);
    int lpos0 = swz * MS;
    int pos0  = pos_base + lpos0;
    int b   = pos0 / DWT;
    int dw0 = pos0 % DWT;

    if (t < MS * NYC) {
        int p = t / NYC, y = t % NYC;
        size_t gi = (((size_t)(b * NYC + y)) * DWT + dw0 + p) * 2;
        float g0 = gtl[gi], g1 = gtl[gi + 1];
        float g2 = gbr[gi], g3 = gbr[gi + 1];
        float area = (g2 - g0) * (g3 - g1) * ((float)HF * (float)WF * 0.25f) + 1e-6f;
        float inv  = (area > 1e-6f) ? (1.0f / area) : 0.0f;
        const float sgn[4] = {1.f, 1.f, -1.f, -1.f};
        float px[4] = {g0, g2, g2, g0};
        float py[4] = {g1, g3, g1, g3};
        #pragma unroll
        for (int q = 0; q < 4; ++q) {
            float x  = (px[q] + 1.0f) * ((float)WF * 0.5f) - 0.5f;
            float yy = (py[q] + 1.0f) * ((float)HF * 0.5f) - 0.5f;
            float x0f = floorf(x), y0f = floorf(yy);
            float wx = x - x0f, wy = yy - y0f;
            float wq[4] = {(1.f-wx)*(1.f-wy), wx*(1.f-wy), (1.f-wx)*wy, wx*wy};
            #pragma unroll
            for (int s = 0; s < 4; ++s) {
                float xi = x0f + (float)(s & 1);
                float yi = y0f + (float)(s >> 1);
                bool valid = (xi >= 0.f) && (xi < (float)WF) && (yi >= 0.f) && (yi < (float)HF);
                int xc = (int)fminf(fmaxf(xi, 0.f), (float)(WF - 1));
                int yc = (int)fminf(fmaxf(yi, 0.f), (float)(HF - 1));
                taps[p][y][q * 4 + s] =
                    make_int2(yc * WF + xc, __float_as_int(valid ? (wq[s] * sgn[q] * inv) : 0.0f));
            }
        }
    }
    __syncthreads();

    int p = t >> 5;
    int c = (t & 31) * 8;
    int lpos = lpos0 + p;
    int mt = lpos >> 4, r = lpos & 15, g = (c >> 3) & 3;
    const _Float16* base = iith + (size_t)b * PLANE * CCH + c;
    ushort_t* vbase = voxf + ((size_t)mt * NKT * 64 + (size_t)(g * 16 + r)) * 8;

    for (int y = 0; y < NYC; ++y) {
        float acc[8] = {0.f,0.f,0.f,0.f,0.f,0.f,0.f,0.f};
        #pragma unroll
        for (int q = 0; q < 16; ++q) {
            int2 tp = taps[p][y][q];
            float wg = __int_as_float(tp.y);
            uint4 hv = *reinterpret_cast<const uint4*>(base + (size_t)tp.x * CCH);
            float2 f;
            f = __half22float2(*reinterpret_cast<__half2*>(&hv.x)); acc[0] += wg*f.x; acc[1] += wg*f.y;
            f = __half22float2(*reinterpret_cast<__half2*>(&hv.y)); acc[2] += wg*f.x; acc[3] += wg*f.y;
            f = __half22float2(*reinterpret_cast<__half2*>(&hv.z)); acc[4] += wg*f.x; acc[5] += wg*f.y;
            f = __half22float2(*reinterpret_cast<__half2*>(&hv.w)); acc[6] += wg*f.x; acc[7] += wg*f.y;
        }
        int kt = (y << 3) + (c >> 5);
        short8 o;
        #pragma unroll
        for (int j = 0; j < 8; ++j) o[j] = (short)f2bf(acc[j]);
        *reinterpret_cast<short8*>(vbase + (size_t)kt * 64 * 8) = o;
    }
}

// ---------------- K7: register-blocked MFMA GEMM (128M x 128N per block) -----
// 4 waves (mi,ni in 2x2); per wave mA=4, nB=4 -> 16 MFMA per 8 loads; depth-2 dbuf
__global__ __launch_bounds__(256)
void k_gemm(const ushort_t* __restrict__ voxf, const ushort_t* __restrict__ wbf,
            const float* __restrict__ bias, float* __restrict__ ortho, int pos_base) {
    int t = threadIdx.x;
    int lane = t & 63, wv = t >> 6;
    int mi = wv >> 1, ni = wv & 1;
    int bx = blockIdx.x;
    int swz = (bx & 7) * (gridDim.x >> 3) + (bx >> 3);   // XCD-chunked
    int nhalf = swz & 1, pm = swz >> 1;
    int lpos0 = pm * 128;
    int pos0 = pos_base + lpos0;
    int b = pos0 / DWT, dw0 = pos0 % DWT;
    int mt0 = (lpos0 >> 4) + mi * 4;
    int nt0 = nhalf * 8 + ni * 4;

    const short8* ap = reinterpret_cast<const short8*>(voxf) + (size_t)mt0 * NKT * 64 + lane;
    const short8* bp = reinterpret_cast<const short8*>(wbf)  + (size_t)nt0 * NKT * 64 + lane;
    const size_t TS = (size_t)NKT * 64;     // tile stride in short8

    f32x4 acc[4][4] = {};
    short8 A0[4], B0[4], A1[4], B1[4];
    #pragma unroll
    for (int i = 0; i < 4; ++i) {
        A0[i] = ap[i * TS];
        B0[i] = bp[i * TS];
        A1[i] = ap[i * TS + 64];
        B1[i] = bp[i * TS + 64];
    }

    for (int kt = 0; kt < NKT; kt += 2) {
        #pragma unroll
        for (int m = 0; m < 4; ++m)
            #pragma unroll
            for (int n = 0; n < 4; ++n)
                acc[m][n] = __builtin_amdgcn_mfma_f32_16x16x32_bf16(A0[m], B0[n], acc[m][n], 0, 0, 0);
        if (kt + 2 < NKT) {
            #pragma unroll
            for (int i = 0; i < 4; ++i) {
                A0[i] = ap[i * TS + (size_t)(kt + 2) * 64];
                B0[i] = bp[i * TS + (size_t)(kt + 2) * 64];
            }
        }
        #pragma unroll
        for (int m = 0; m < 4; ++m)
            #pragma unroll
            for (int n = 0; n < 4; ++n)
                acc[m][n] = __builtin_amdgcn_mfma_f32_16x16x32_bf16(A1[m], B1[n], acc[m][n], 0, 0, 0);
        if (kt + 3 < NKT) {
            #pragma unroll
            for (int i = 0; i < 4; ++i) {
                A1[i] = ap[i * TS + (size_t)(kt + 3) * 64];
                B1[i] = bp[i * TS + (size_t)(kt + 3) * 64];
            }
        }
    }

    int r = lane & 15, gq = lane >> 4;
    #pragma unroll
    for (int n = 0; n < 4; ++n) {
        int co = nhalf * 128 + (ni * 4 + n) * 16 + r;
        float bv = bias[co];
        float* ob = ortho + ((size_t)(b * CCH + co)) * DWT + dw0 + gq * 4;
        #pragma unroll
        for (int m = 0; m < 4; ++m) {
            float4 o = make_float4(fmaxf(acc[m][n][0] + bv, 0.f), fmaxf(acc[m][n][1] + bv, 0.f),
                                   fmaxf(acc[m][n][2] + bv, 0.f), fmaxf(acc[m][n][3] + bv, 0.f));
            *reinterpret_cast<float4*>(ob + (mi * 4 + m) * 16) = o;
        }
    }
}

extern "C" void kernel_launch(void* const* d_in, const int* in_sizes, int n_in,
                              void* d_out, int out_size, void* d_ws, size_t ws_size,
                              hipStream_t stream) {
    const float* features = (const float*)d_in[0];
    const float* calib    = (const float*)d_in[1];
    const float* grid     = (const float*)d_in[2];
    const float* w        = (const float*)d_in[3];
    const float* bias     = (const float*)d_in[4];

    float* out   = (float*)d_out;
    float* ortho = out;
    float* ii    = out + (size_t)8388608;
    float* gtl   = out + (size_t)24117248;
    float* gbr   = out + (size_t)24576000;
    float* gtr   = out + (size_t)25034752;
    float* gbl   = out + (size_t)25493504;

    ushort_t* wbf  = (ushort_t*)d_ws;
    _Float16* iith = (_Float16*)((char*)d_ws + WBF_BYTES);
    ushort_t* voxf = (ushort_t*)((char*)d_ws + WBF_BYTES + IITH_BYTES);

    k_integral<<<BB * CCH, 512, 0, stream>>>(features, ii);
    k_geom    <<<(BB * NYC * DWT + 255) / 256, 256, 0, stream>>>(calib, grid, gtl, gbr, gtr, gbl);
    k_prepack <<<(16 * NKT * 64 + 255) / 256, 256, 0, stream>>>(w, wbf);
    dim3 gT(WF / 32, CCH / 32, BB * HF);
    k_transpose<<<gT, dim3(32, 8), 0, stream>>>(ii, iith);

    size_t vox_all = (size_t)POS_TOTAL * KDIM * 2;             // 117 MB
    int nch = (ws_size >= WBF_BYTES + IITH_BYTES + vox_all) ? 1 : 4;
    int cpos = POS_TOTAL / nch;
    for (int cidx = 0; cidx < nch; ++cidx) {
        int pb = cidx * cpos;
        k_sample<<<cpos / MS, 256, 0, stream>>>(iith, gtl, gbr, voxf, pb);
        k_gemm  <<<(cpos / 128) * 2, 256, 0, stream>>>(voxf, wbf, bias, ortho, pb);
    }
}